// Round 1
// baseline (928.364 us; speedup 1.0000x reference)
//
#include <hip/hip_runtime.h>
#include <hip/hip_bf16.h>
#include <cstdint>
#include <cstddef>

// Problem constants
constexpr int   Bm = 1024;      // batch (M)
constexpr int   Dk = 512;       // feature dim (K)
constexpr int   Cn = 100000;    // classes (N)
constexpr float S_SCALE = 30.0f;
constexpr float MARGIN  = 0.4f;

static_assert(Cn % 4 == 0, "N must be multiple of 4 for float4 loads");

typedef __bf16 bf16_t;
typedef __bf16 bf16x4 __attribute__((ext_vector_type(4)));
typedef __bf16 bf16x8 __attribute__((ext_vector_type(8)));
typedef float  f32x4  __attribute__((ext_vector_type(4)));

constexpr int BN    = 128;          // N tile
constexpr int BK    = 32;           // K tile
constexpr int NSTEP = Dk / BK;      // 16
constexpr int NT    = (Cn + BN - 1) / BN;   // 782 n-tiles (last has 32 valid cols)
constexpr int NTP   = 784;          // padded partials stride
constexpr int LDB   = 40;           // padded LDS row stride for B[n][k] (elements)

// ---------------------------------------------------------------------------
// prep: L2-normalize rows of x, store bf16. One wave per row.
// ---------------------------------------------------------------------------
__global__ __launch_bounds__(64) void k_prep_x(const float* __restrict__ x,
                                               bf16_t* __restrict__ Xbf) {
    const int row  = blockIdx.x;
    const int lane = threadIdx.x;
    const float* xp = x + (size_t)row * Dk + lane * 8;
    float4 a = *(const float4*)xp;
    float4 b = *(const float4*)(xp + 4);
    float s = a.x*a.x + a.y*a.y + a.z*a.z + a.w*a.w
            + b.x*b.x + b.y*b.y + b.z*b.z + b.w*b.w;
    #pragma unroll
    for (int off = 1; off < 64; off <<= 1) s += __shfl_xor(s, off);
    const float inv = rsqrtf(fmaxf(s, 1e-24f));   // == 1/clip(||x||,1e-12)
    bf16x8 v;
    v[0] = (bf16_t)(a.x * inv); v[1] = (bf16_t)(a.y * inv);
    v[2] = (bf16_t)(a.z * inv); v[3] = (bf16_t)(a.w * inv);
    v[4] = (bf16_t)(b.x * inv); v[5] = (bf16_t)(b.y * inv);
    v[6] = (bf16_t)(b.z * inv); v[7] = (bf16_t)(b.w * inv);
    *(bf16x8*)(Xbf + (size_t)row * Dk + lane * 8) = v;
}

// ---------------------------------------------------------------------------
// fused GEMM: cossim = clip((x/|x|) @ (W/|w_col|), +-1); also per-row partial
// sums of exp(S*cossim) into part[m][nt].
// Grid mapping: id%8 -> XCD (round-robin dispatch), so the 8 m-blocks of one
// n-tile are consecutive on ONE XCD -> W strip read from HBM once, 7x from L2.
// ---------------------------------------------------------------------------
__global__ __launch_bounds__(256) void k_gemm(const float* __restrict__ W,
                                              const bf16_t* __restrict__ Xbf,
                                              float* __restrict__ out,
                                              float* __restrict__ part) {
    __shared__ bf16_t Blds[BN * LDB];      // B[n][k] bf16, padded rows
    __shared__ float  nsqbuf[BN * 8];      // per-(col, kg) norm^2 partials
    __shared__ float  wninv[BN];           // 1/||w_col||
    __shared__ float  rsbuf[128 * 2];      // per-row exp partials, [row][wn]

    const int id    = blockIdx.x;
    const int nt    = (id >> 6) * 8 + (id & 7);
    const int mt8   = (id >> 3) & 7;
    if (nt >= NT) return;
    const int n0 = nt * BN;
    const int m0 = mt8 * 128;

    const int tid  = threadIdx.x;
    const int wave = tid >> 6, lane = tid & 63;
    const int wm   = wave >> 1, wn = wave & 1;
    const int quad = lane >> 4, l16 = lane & 15;

    // staging mapping: thread -> 4 cols x 4 rows of the 32x128 W tile
    const int ng = tid >> 3, kg = tid & 7;
    const int n_loc = ng * 4, k_loc = kg * 4;
    const bool svalid = (n0 + n_loc) < Cn;
    const float* wrow = W + (size_t)k_loc * Cn + (n0 + n_loc);

    f32x4 acc[4][4];
    #pragma unroll
    for (int i = 0; i < 4; ++i)
        #pragma unroll
        for (int j = 0; j < 4; ++j) acc[i][j] = (f32x4){0.f, 0.f, 0.f, 0.f};

    float nsq0 = 0.f, nsq1 = 0.f, nsq2 = 0.f, nsq3 = 0.f;

    const float4 fz = make_float4(0.f, 0.f, 0.f, 0.f);
    float4 r0 = fz, r1 = fz, r2 = fz, r3 = fz;
    if (svalid) {
        r0 = *(const float4*)(wrow);
        r1 = *(const float4*)(wrow + (size_t)Cn);
        r2 = *(const float4*)(wrow + (size_t)2 * Cn);
        r3 = *(const float4*)(wrow + (size_t)3 * Cn);
    }

    const bf16_t* abase = Xbf + (size_t)(m0 + wm * 64 + l16) * Dk + quad * 8;

    #pragma unroll 2
    for (int step = 0; step < NSTEP; ++step) {
        __syncthreads();   // prev iteration's fragment reads done
        // column-norm accumulation (fp32, matches reference norms)
        nsq0 += r0.x*r0.x + r1.x*r1.x + r2.x*r2.x + r3.x*r3.x;
        nsq1 += r0.y*r0.y + r1.y*r1.y + r2.y*r2.y + r3.y*r3.y;
        nsq2 += r0.z*r0.z + r1.z*r1.z + r2.z*r2.z + r3.z*r3.z;
        nsq3 += r0.w*r0.w + r1.w*r1.w + r2.w*r2.w + r3.w*r3.w;
        // in-register 4x4 transpose -> B[n][k] bf16
        {
            bf16x4 p;
            p[0]=(bf16_t)r0.x; p[1]=(bf16_t)r1.x; p[2]=(bf16_t)r2.x; p[3]=(bf16_t)r3.x;
            *(bf16x4*)&Blds[(n_loc + 0) * LDB + k_loc] = p;
            p[0]=(bf16_t)r0.y; p[1]=(bf16_t)r1.y; p[2]=(bf16_t)r2.y; p[3]=(bf16_t)r3.y;
            *(bf16x4*)&Blds[(n_loc + 1) * LDB + k_loc] = p;
            p[0]=(bf16_t)r0.z; p[1]=(bf16_t)r1.z; p[2]=(bf16_t)r2.z; p[3]=(bf16_t)r3.z;
            *(bf16x4*)&Blds[(n_loc + 2) * LDB + k_loc] = p;
            p[0]=(bf16_t)r0.w; p[1]=(bf16_t)r1.w; p[2]=(bf16_t)r2.w; p[3]=(bf16_t)r3.w;
            *(bf16x4*)&Blds[(n_loc + 3) * LDB + k_loc] = p;
        }
        __syncthreads();   // tile visible

        // prefetch next B tile into VGPRs (overlaps the MFMA phase)
        float4 q0 = fz, q1 = fz, q2 = fz, q3 = fz;
        if ((step + 1 < NSTEP) && svalid) {
            const float* pp = wrow + (size_t)((step + 1) * BK) * Cn;
            q0 = *(const float4*)(pp);
            q1 = *(const float4*)(pp + (size_t)Cn);
            q2 = *(const float4*)(pp + (size_t)2 * Cn);
            q3 = *(const float4*)(pp + (size_t)3 * Cn);
        }

        // A fragments straight from global (X is L2-hot: 1 MB, reused 782x)
        const bf16_t* ab = abase + step * BK;
        bf16x8 af[4];
        #pragma unroll
        for (int mt = 0; mt < 4; ++mt)
            af[mt] = *(const bf16x8*)(ab + (size_t)mt * 16 * Dk);
        bf16x8 bfr[4];
        #pragma unroll
        for (int nl = 0; nl < 4; ++nl)
            bfr[nl] = *(const bf16x8*)&Blds[(wn * 64 + nl * 16 + l16) * LDB + quad * 8];

        #pragma unroll
        for (int mt = 0; mt < 4; ++mt)
            #pragma unroll
            for (int nl = 0; nl < 4; ++nl)
                acc[mt][nl] = __builtin_amdgcn_mfma_f32_16x16x32_bf16(
                    af[mt], bfr[nl], acc[mt][nl], 0, 0, 0);

        r0 = q0; r1 = q1; r2 = q2; r3 = q3;
    }

    // reduce column norms
    __syncthreads();
    nsqbuf[(n_loc + 0) * 8 + kg] = nsq0;
    nsqbuf[(n_loc + 1) * 8 + kg] = nsq1;
    nsqbuf[(n_loc + 2) * 8 + kg] = nsq2;
    nsqbuf[(n_loc + 3) * 8 + kg] = nsq3;
    __syncthreads();
    if (tid < BN) {
        float s = 0.f;
        #pragma unroll
        for (int i = 0; i < 8; ++i) s += nsqbuf[tid * 8 + i];
        wninv[tid] = rsqrtf(fmaxf(s, 1e-24f));
    }
    __syncthreads();

    // epilogue: scale, clip, store cossim; accumulate exp row-sums
    float eacc[4][4];
    #pragma unroll
    for (int i = 0; i < 4; ++i)
        #pragma unroll
        for (int j = 0; j < 4; ++j) eacc[i][j] = 0.f;

    #pragma unroll
    for (int mt = 0; mt < 4; ++mt) {
        const int mrow = m0 + wm * 64 + mt * 16 + quad * 4;
        #pragma unroll
        for (int nl = 0; nl < 4; ++nl) {
            const int ncol = wn * 64 + nl * 16 + l16;
            const int n = n0 + ncol;
            if (n < Cn) {
                const float inv = wninv[ncol];
                #pragma unroll
                for (int reg = 0; reg < 4; ++reg) {
                    float v = acc[mt][nl][reg] * inv;
                    v = fminf(fmaxf(v, -1.f), 1.f);
                    out[(size_t)(mrow + reg) * Cn + n] = v;
                    eacc[mt][reg] += __expf(S_SCALE * v);
                }
            }
        }
    }
    // reduce exp partials over the 16 columns of each quad
    #pragma unroll
    for (int mt = 0; mt < 4; ++mt)
        #pragma unroll
        for (int reg = 0; reg < 4; ++reg) {
            float e = eacc[mt][reg];
            #pragma unroll
            for (int off = 1; off < 16; off <<= 1) e += __shfl_xor(e, off);
            if (l16 == 0)
                rsbuf[(wm * 64 + mt * 16 + quad * 4 + reg) * 2 + wn] = e;
        }
    __syncthreads();
    if (tid < 128)
        part[(size_t)(m0 + tid) * NTP + nt] = rsbuf[tid * 2] + rsbuf[tid * 2 + 1];
}

// ---------------------------------------------------------------------------
// per-row: sum 782 partials, gather target, compute per-row loss term
// ---------------------------------------------------------------------------
__global__ __launch_bounds__(256) void k_row(const float* __restrict__ part,
                                             const float* __restrict__ out,
                                             const int* __restrict__ label,
                                             float* __restrict__ Lbuf) {
    const int b = blockIdx.x, tid = threadIdx.x;
    float s = 0.f;
    const float* p = part + (size_t)b * NTP;
    for (int i = tid; i < NT; i += 256) s += p[i];
    #pragma unroll
    for (int off = 1; off < 64; off <<= 1) s += __shfl_xor(s, off);
    __shared__ float wsum[4];
    if ((tid & 63) == 0) wsum[tid >> 6] = s;
    __syncthreads();
    if (tid == 0) {
        const float rowsum = wsum[0] + wsum[1] + wsum[2] + wsum[3];
        const int c = label[b];
        const float tgt = out[(size_t)b * Cn + c];
        const float num = S_SCALE * (tgt - MARGIN);
        const float excl = rowsum - __expf(S_SCALE * tgt);
        Lbuf[b] = num - __logf(__expf(num) + excl);
    }
}

// ---------------------------------------------------------------------------
// final: loss = -mean(L)
// ---------------------------------------------------------------------------
__global__ __launch_bounds__(256) void k_loss(const float* __restrict__ Lbuf,
                                              float* __restrict__ out) {
    const int tid = threadIdx.x;
    float s = 0.f;
    for (int i = tid; i < Bm; i += 256) s += Lbuf[i];
    #pragma unroll
    for (int off = 1; off < 64; off <<= 1) s += __shfl_xor(s, off);
    __shared__ float wsum[4];
    if ((tid & 63) == 0) wsum[tid >> 6] = s;
    __syncthreads();
    if (tid == 0)
        out[(size_t)Bm * Cn] = -(wsum[0] + wsum[1] + wsum[2] + wsum[3]) / (float)Bm;
}

// ---------------------------------------------------------------------------
extern "C" void kernel_launch(void* const* d_in, const int* in_sizes, int n_in,
                              void* d_out, int out_size, void* d_ws, size_t ws_size,
                              hipStream_t stream) {
    const float* x     = (const float*)d_in[0];
    const float* W     = (const float*)d_in[1];
    const int*   label = (const int*)d_in[2];
    float* out = (float*)d_out;

    bf16_t* Xbf = (bf16_t*)d_ws;                                   // 1 MB
    float*  part = (float*)((char*)d_ws + (1 << 20));              // 1024*784*4 B
    float*  Lbuf = (float*)((char*)d_ws + (1 << 20) + (size_t)Bm * NTP * 4);

    k_prep_x<<<Bm, 64, 0, stream>>>(x, Xbf);
    k_gemm<<<98 * 64, 256, 0, stream>>>(W, Xbf, out, part);  // 6272 blocks, 16 idle
    k_row<<<Bm, 256, 0, stream>>>(part, out, label, Lbuf);
    k_loss<<<1, 256, 0, stream>>>(Lbuf, out);
}